// Round 6
// baseline (797.482 us; speedup 1.0000x reference)
//
#include <hip/hip_runtime.h>
#include <hip/hip_bf16.h>

#define NN 50000
#define NE 30000
#define NT 8
#define HH 128
#define NB 64
#define CONT 96
#define TPB 16
#define EDGES (NT * NE)
#define SBLK 512
#define SNB ((NN + SBLK - 1) / SBLK)   // 98
#define RCH 8                          // readout chunks per example
#define NTILE (NN / 16)                // 3125

typedef __attribute__((ext_vector_type(8))) short short8;
typedef __attribute__((ext_vector_type(4))) float f32x4;

__device__ __forceinline__ float sigm(float x) { return 1.f / (1.f + __expf(-x)); }
__device__ __forceinline__ unsigned short bfbits(float x) {
  __hip_bfloat16 b = __float2bfloat16(x);
  return *(unsigned short*)&b;
}

// ---------------------------------------------------------------- init (bf16 only)
__global__ __launch_bounds__(256) void init_kernel(
    const int* __restrict__ cid, const int* __restrict__ tg,
    const float* __restrict__ ctab, const float* __restrict__ ttab,
    __hip_bfloat16* __restrict__ sbf, __hip_bfloat16* __restrict__ ibf)
{
  int i = blockIdx.x * 256 + threadIdx.x;
  if (i >= NN * HH) return;
  int n = i >> 7, d = i & 127;
  float v;
  if (d < CONT) v = ctab[(size_t)cid[n] * CONT + d];
  else          v = ttab[(size_t)tg[n] * 32 + (d - CONT)];
  __hip_bfloat16 b = __float2bfloat16(v);
  sbf[i] = b;
  ibf[i] = b;
}

// ---------------------------------------------------------------- CSR build
__global__ __launch_bounds__(256) void hist_kernel(
    const int* __restrict__ etgt, int* __restrict__ cnt)
{
  int i = blockIdx.x * 256 + threadIdx.x;
  if (i >= EDGES) return;
  atomicAdd(&cnt[etgt[i]], 1);
}

__global__ __launch_bounds__(SBLK) void scanA_kernel(
    const int* __restrict__ cnt, int* __restrict__ row_ptr, int* __restrict__ bsum)
{
  __shared__ int sm[SBLK];
  const int tid = threadIdx.x;
  const int i = blockIdx.x * SBLK + tid;
  int v = (i < NN) ? cnt[i] : 0;
  sm[tid] = v;
  __syncthreads();
  for (int off = 1; off < SBLK; off <<= 1) {
    int t = (tid >= off) ? sm[tid - off] : 0;
    __syncthreads();
    sm[tid] += t;
    __syncthreads();
  }
  if (i < NN) row_ptr[i] = sm[tid] - v;
  if (tid == SBLK - 1) bsum[blockIdx.x] = sm[tid];
}

__global__ __launch_bounds__(128) void scanB_kernel(
    const int* __restrict__ bsum, int* __restrict__ boff, int* __restrict__ row_ptr)
{
  __shared__ int sm[128];
  const int tid = threadIdx.x;
  int v = (tid < SNB) ? bsum[tid] : 0;
  sm[tid] = v;
  __syncthreads();
  for (int off = 1; off < 128; off <<= 1) {
    int t = (tid >= off) ? sm[tid - off] : 0;
    __syncthreads();
    sm[tid] += t;
    __syncthreads();
  }
  if (tid < SNB) boff[tid] = sm[tid] - v;
  if (tid == 127) row_ptr[NN] = sm[127];
}

__global__ __launch_bounds__(SBLK) void scanC_kernel(
    int* __restrict__ row_ptr, int* __restrict__ cnt2, const int* __restrict__ boff)
{
  int i = blockIdx.x * SBLK + threadIdx.x;
  if (i >= NN) return;
  int r = row_ptr[i] + boff[blockIdx.x];
  row_ptr[i] = r;
  cnt2[i] = r;
}

__global__ __launch_bounds__(256) void scatter_kernel(
    const int* __restrict__ etgt, int* __restrict__ cnt2, int* __restrict__ perm)
{
  int i = blockIdx.x * 256 + threadIdx.x;
  if (i >= EDGES) return;
  perm[i] = atomicAdd(&cnt2[etgt[i]], 1);
}

__global__ __launch_bounds__(128) void exbound_kernel(
    const int* __restrict__ n2e, int* __restrict__ ebnd)
{
  int ex = threadIdx.x;
  if (ex > NB) return;
  int lo = 0, hi = NN;
  while (lo < hi) { int mid = (lo + hi) >> 1; if (n2e[mid] < ex) lo = mid + 1; else hi = mid; }
  ebnd[ex] = lo;
}

// ---------------------------------------------------------------- all weight swizzles
__device__ __forceinline__ void gru_swz_one(
    const float* __restrict__ W, __hip_bfloat16* __restrict__ out, int KSL, int mode, int i)
{
  int j = i & 7, lane = (i >> 3) & 63, kk = (i >> 9) % KSL, nt = i / (KSL * 512);
  int hi = lane >> 4, lo = lane & 15;
  int p = kk * 32 + hi * 8 + j;
  int k;
  if (mode == 0)      k = p;
  else if (mode == 1) k = (p & 7) * 16 + (p >> 3);
  else                k = (p < 128) ? p : 128 + ((p - 128) & 7) * 16 + ((p - 128) >> 3);
  out[i] = __float2bfloat16(W[(size_t)k * 384 + nt * 16 + lo]);
}

__global__ __launch_bounds__(256) void wswz_all_kernel(
    const float* __restrict__ msgW, __hip_bfloat16* __restrict__ wswz,
    const float* __restrict__ g0Wih, __hip_bfloat16* __restrict__ w0ih,
    const float* __restrict__ g0Whh, __hip_bfloat16* __restrict__ w0hh,
    const float* __restrict__ g1Wih, __hip_bfloat16* __restrict__ w1ih,
    const float* __restrict__ g1Whh, __hip_bfloat16* __restrict__ w1hh)
{
  int i = blockIdx.x * 256 + threadIdx.x;   // 507904 total
  if (i < 262144) {
    int j = i & 7, lane = (i >> 3) & 63, kk = (i >> 9) & 3, nt = (i >> 11) & 7, lt = i >> 14;
    int hi = lane >> 4, lo = lane & 15;
    int k = kk * 32 + hi * 8 + j;
    wswz[i] = __float2bfloat16(msgW[((size_t)lt * HH + k) * HH + nt * 16 + lo]);
    return;
  }
  i -= 262144;
  if (i < 49152)  { gru_swz_one(g0Wih, w0ih, 4, 1, i); return; }
  i -= 49152;
  if (i < 49152)  { gru_swz_one(g0Whh, w0hh, 4, 0, i); return; }
  i -= 49152;
  if (i < 98304)  { gru_swz_one(g1Wih, w1ih, 8, 2, i); return; }
  i -= 98304;
  if (i < 49152)  { gru_swz_one(g1Whh, w1hh, 4, 0, i); return; }
}

// ---------------------------------------------------------------- messages (MFMA)
__global__ __launch_bounds__(256) void msg_mfma_kernel(
    const __hip_bfloat16* __restrict__ sbf, const int* __restrict__ esrc,
    const int* __restrict__ perm, const __hip_bfloat16* __restrict__ wswz,
    const float* __restrict__ ball, __hip_bfloat16* __restrict__ msgs, int layer)
{
  __shared__ short8 Wl[8 * 4 * 64];  // 32KB
  const int t = blockIdx.y;
  {
    const float4* wg = (const float4*)(wswz + (size_t)(layer * NT + t) * 16384);
    float4* wl = (float4*)Wl;
    for (int i = threadIdx.x; i < 2048; i += 256) wl[i] = wg[i];
  }
  const int lane = threadIdx.x & 63;
  const int wv   = threadIdx.x >> 6;
  const int hi = lane >> 4, lo = lane & 15;
  float bias_v[8];
#pragma unroll
  for (int nt = 0; nt < 8; ++nt)
    bias_v[nt] = ball[(layer * NT + t) * HH + nt * 16 + lo];
  __syncthreads();

  const int tile_end = min((int)(blockIdx.x + 1) * TPB, NE / 16);
  for (int tile = blockIdx.x * TPB + wv; tile < tile_end; tile += 4) {
    const int e0 = tile * 16;
    const int src = esrc[t * NE + e0 + lo];
    const short* srow = (const short*)(sbf + (size_t)src * HH);
    short8 a[4];
#pragma unroll
    for (int kk = 0; kk < 4; ++kk)
      a[kk] = *(const short8*)(srow + kk * 32 + hi * 8);
    int slot[4];
#pragma unroll
    for (int r = 0; r < 4; ++r) slot[r] = perm[t * NE + e0 + hi * 4 + r];
    f32x4 acc[8];
#pragma unroll
    for (int nt = 0; nt < 8; ++nt) acc[nt] = (f32x4){0.f, 0.f, 0.f, 0.f};
#pragma unroll
    for (int nt = 0; nt < 8; ++nt)
#pragma unroll
      for (int kk = 0; kk < 4; ++kk)
        acc[nt] = __builtin_amdgcn_mfma_f32_16x16x32_bf16(
            a[kk], Wl[(nt * 4 + kk) * 64 + lane], acc[nt], 0, 0, 0);
#pragma unroll
    for (int r = 0; r < 4; ++r) {
      short8 m;
#pragma unroll
      for (int nt = 0; nt < 8; ++nt)
        ((unsigned short*)&m)[nt] = bfbits(acc[nt][r] + bias_v[nt]);
      *(short8*)((short*)msgs + (size_t)slot[r] * HH + lo * 8) = m;
    }
  }
}

// ---------------------------------------------------------------- reduce (CSR gather-sum)
__global__ __launch_bounds__(256) void reduce_kernel(
    const __hip_bfloat16* __restrict__ msgs, const int* __restrict__ row_ptr,
    __hip_bfloat16* __restrict__ agg)
{
  const int lane = threadIdx.x & 63;
  const int n = blockIdx.x * 4 + (threadIdx.x >> 6);
  if (n >= NN) return;
  const int b = row_ptr[n], e = row_ptr[n + 1];
  float a0 = 0.f, a1 = 0.f;
  for (int i = b; i < e; ++i) {
    unsigned int v = *(const unsigned int*)((const short*)msgs + (size_t)i * HH + lane * 2);
    a0 += __uint_as_float(v << 16);
    a1 += __uint_as_float(v & 0xffff0000u);
  }
  unsigned int o = ((unsigned int)bfbits(a1) << 16) | bfbits(a0);
  *(unsigned int*)((short*)agg + (size_t)n * HH + lane * 2) = o;
}

// ---------------------------------------------------------------- GRU (MFMA, 1 tile/wave, bf16 state ping-pong)
template <int KSL>
__global__ __launch_bounds__(256) void gru_mfma_kernel(
    const __hip_bfloat16* __restrict__ agg,     // sigma order
    const __hip_bfloat16* __restrict__ ibf,     // row-major (layer1)
    const __hip_bfloat16* __restrict__ hbf,     // current state bf16 (read)
    const __hip_bfloat16* __restrict__ Wih_s,
    const __hip_bfloat16* __restrict__ Whh_s,
    const float* __restrict__ bih, const float* __restrict__ bhh,
    __hip_bfloat16* __restrict__ sbf_out)       // next state bf16 (write)
{
  const int lane = threadIdx.x & 63;
  const int wv   = threadIdx.x >> 6;
  const int tile = blockIdx.x * 4 + wv;
  if (tile >= NTILE) return;
  const int nb = tile * 16;
  const int hi = lane >> 4, lo = lane & 15;

  short8 ax[KSL], ah[4];
  {
    const short* arow = (const short*)(agg + (size_t)(nb + lo) * HH);
    const short* hrow = (const short*)(hbf + (size_t)(nb + lo) * HH);
    if (KSL == 8) {
      const short* irow = (const short*)(ibf + (size_t)(nb + lo) * HH);
#pragma unroll
      for (int kk = 0; kk < 4; ++kk) {
        ax[kk]     = *(const short8*)(irow + kk * 32 + hi * 8);
        ax[kk + 4] = *(const short8*)(arow + kk * 32 + hi * 8);
      }
    } else {
#pragma unroll
      for (int kk = 0; kk < 4; ++kk)
        ax[kk] = *(const short8*)(arow + kk * 32 + hi * 8);
    }
#pragma unroll
    for (int kk = 0; kk < 4; ++kk)
      ah[kk] = *(const short8*)(hrow + kk * 32 + hi * 8);
  }

  const short8* Bih = (const short8*)Wih_s;
  const short8* Bhh = (const short8*)Whh_s;

#pragma unroll
  for (int dt = 0; dt < 8; ++dt) {
    f32x4 gi[3], gh[3];
#pragma unroll
    for (int g = 0; g < 3; ++g) {
      gi[g] = (f32x4){0.f, 0.f, 0.f, 0.f};
      gh[g] = (f32x4){0.f, 0.f, 0.f, 0.f};
    }
#pragma unroll
    for (int kk = 0; kk < KSL; ++kk)
#pragma unroll
      for (int g = 0; g < 3; ++g)
        gi[g] = __builtin_amdgcn_mfma_f32_16x16x32_bf16(
            ax[kk], Bih[((size_t)(dt + 8 * g) * KSL + kk) * 64 + lane], gi[g], 0, 0, 0);
#pragma unroll
    for (int kk = 0; kk < 4; ++kk)
#pragma unroll
      for (int g = 0; g < 3; ++g)
        gh[g] = __builtin_amdgcn_mfma_f32_16x16x32_bf16(
            ah[kk], Bhh[((size_t)(dt + 8 * g) * 4 + kk) * 64 + lane], gh[g], 0, 0, 0);
    const int c = dt * 16 + lo;
    const float bir = bih[c], biz = bih[c + 128], bin = bih[c + 256];
    const float bhr = bhh[c], bhz = bhh[c + 128], bhn = bhh[c + 256];
#pragma unroll
    for (int r = 0; r < 4; ++r) {
      const int node = nb + hi * 4 + r;
      const float rg = sigm(gi[0][r] + bir + gh[0][r] + bhr);
      const float zg = sigm(gi[1][r] + biz + gh[1][r] + bhz);
      const float ng = tanhf(gi[2][r] + bin + rg * (gh[2][r] + bhn));
      const float hc = __bfloat162float(hbf[(size_t)node * HH + c]);
      sbf_out[(size_t)node * HH + c] = __float2bfloat16((1.f - zg) * ng + zg * hc);
    }
  }
}

// ---------------------------------------------------------------- readout (bf16 input)
__global__ __launch_bounds__(256) void readout_kernel(
    const __hip_bfloat16* __restrict__ sbf, const int* __restrict__ ebnd,
    const float* __restrict__ rw, const float* __restrict__ rb,
    float* __restrict__ out, int coff)
{
  __shared__ float sm[4][128];
  const int ex = blockIdx.x / RCH, ch = blockIdx.x % RCH;
  const int s = ebnd[ex], e = ebnd[ex + 1];
  const int lane = threadIdx.x & 63;
  const int wv   = threadIdx.x >> 6;
  const float w0 = rw[2 * lane], w1 = rw[2 * lane + 1], rbv = rb[0];
  float a0 = 0.f, a1 = 0.f;
  for (int n = s + ch * 4 + wv; n < e; n += 4 * RCH) {
    unsigned int v = *(const unsigned int*)((const short*)sbf + (size_t)n * HH + lane * 2);
    const float s0 = __uint_as_float(v << 16);
    const float s1 = __uint_as_float(v & 0xffff0000u);
    float p = s0 * w0 + s1 * w1;
#pragma unroll
    for (int o = 32; o; o >>= 1) p += __shfl_xor(p, o, 64);
    const float g = sigm(p + rbv);
    a0 += g * s0;
    a1 += g * s1;
  }
  sm[wv][2 * lane] = a0;
  sm[wv][2 * lane + 1] = a1;
  __syncthreads();
  if (wv == 0) {
    const int c0 = 2 * lane, c1 = 2 * lane + 1;
    float v0 = sm[0][c0] + sm[1][c0] + sm[2][c0] + sm[3][c0];
    float v1 = sm[0][c1] + sm[1][c1] + sm[2][c1] + sm[3][c1];
    atomicAdd(&out[(size_t)ex * (2 * HH) + coff + c0], v0);
    atomicAdd(&out[(size_t)ex * (2 * HH) + coff + c1], v1);
  }
}

// ---------------------------------------------------------------- launch
extern "C" void kernel_launch(void* const* d_in, const int* in_sizes, int n_in,
                              void* d_out, int out_size, void* d_ws, size_t ws_size,
                              hipStream_t stream)
{
  const int*   cid   = (const int*)d_in[0];
  const int*   tg    = (const int*)d_in[1];
  const int*   esrc  = (const int*)d_in[2];
  const int*   etgt  = (const int*)d_in[3];
  const int*   n2e   = (const int*)d_in[4];
  const float* ctab  = (const float*)d_in[5];
  const float* ttab  = (const float*)d_in[6];
  const float* msgW  = (const float*)d_in[7];
  const float* msgb  = (const float*)d_in[8];
  const float* g0Wih = (const float*)d_in[9];
  const float* g0Whh = (const float*)d_in[10];
  const float* g0bih = (const float*)d_in[11];
  const float* g0bhh = (const float*)d_in[12];
  const float* g1Wih = (const float*)d_in[13];
  const float* g1Whh = (const float*)d_in[14];
  const float* g1bih = (const float*)d_in[15];
  const float* g1bhh = (const float*)d_in[16];
  const float* r1w   = (const float*)d_in[17];
  const float* r1b   = (const float*)d_in[18];
  const float* r2w   = (const float*)d_in[19];
  const float* r2b   = (const float*)d_in[20];

  float* out = (float*)d_out;
  __hip_bfloat16* sb0  = (__hip_bfloat16*)d_ws;
  __hip_bfloat16* sb1  = sb0 + (size_t)NN * HH;
  __hip_bfloat16* ibf  = sb1 + (size_t)NN * HH;
  __hip_bfloat16* agg  = ibf + (size_t)NN * HH;
  __hip_bfloat16* msgs = agg + (size_t)NN * HH;
  __hip_bfloat16* wswz = msgs + (size_t)EDGES * HH;
  __hip_bfloat16* w0ih = wswz + 262144;
  __hip_bfloat16* w0hh = w0ih + 24 * 4 * 512;
  __hip_bfloat16* w1ih = w0hh + 24 * 4 * 512;
  __hip_bfloat16* w1hh = w1ih + 24 * 8 * 512;
  int* row_ptr = (int*)(w1hh + 24 * 4 * 512);
  int* cnt     = row_ptr + NN + 1;
  int* cnt2    = cnt + NN;
  int* perm    = cnt2 + NN;
  int* bsum    = perm + EDGES;
  int* boff    = bsum + SNB;
  int* ebnd    = boff + SNB;

  hipMemsetAsync(d_out, 0, (size_t)NB * 2 * HH * sizeof(float), stream);
  hipMemsetAsync(cnt, 0, (size_t)NN * sizeof(int), stream);
  const int eblocks = (EDGES + 255) / 256;
  hist_kernel<<<eblocks, 256, 0, stream>>>(etgt, cnt);
  scanA_kernel<<<SNB, SBLK, 0, stream>>>(cnt, row_ptr, bsum);
  scanB_kernel<<<1, 128, 0, stream>>>(bsum, boff, row_ptr);
  scanC_kernel<<<SNB, SBLK, 0, stream>>>(row_ptr, cnt2, boff);
  scatter_kernel<<<eblocks, 256, 0, stream>>>(etgt, cnt2, perm);
  exbound_kernel<<<1, 128, 0, stream>>>(n2e, ebnd);

  wswz_all_kernel<<<507904 / 256, 256, 0, stream>>>(msgW, wswz, g0Wih, w0ih, g0Whh, w0hh,
                                                    g1Wih, w1ih, g1Whh, w1hh);
  init_kernel<<<(NN * HH + 255) / 256, 256, 0, stream>>>(cid, tg, ctab, ttab, sb0, ibf);

  dim3 mgrid((NE / 16 + TPB - 1) / TPB, NT);
  const int rblocks = (NN + 3) / 4;
  const int gblocks = (NTILE + 3) / 4;
  __hip_bfloat16* cur = sb0;
  __hip_bfloat16* nxt = sb1;
  for (int s = 0; s < 3; ++s) {
    msg_mfma_kernel<<<mgrid, 256, 0, stream>>>(cur, esrc, perm, wswz, msgb, msgs, 0);
    reduce_kernel<<<rblocks, 256, 0, stream>>>(msgs, row_ptr, agg);
    gru_mfma_kernel<4><<<gblocks, 256, 0, stream>>>(agg, ibf, cur, w0ih, w0hh,
                                                    g0bih, g0bhh, nxt);
    __hip_bfloat16* t = cur; cur = nxt; nxt = t;
  }
  readout_kernel<<<NB * RCH, 256, 0, stream>>>(cur, ebnd, r1w, r1b, out, 0);

  for (int s = 0; s < 3; ++s) {
    msg_mfma_kernel<<<mgrid, 256, 0, stream>>>(cur, esrc, perm, wswz, msgb, msgs, 1);
    reduce_kernel<<<rblocks, 256, 0, stream>>>(msgs, row_ptr, agg);
    gru_mfma_kernel<8><<<gblocks, 256, 0, stream>>>(agg, ibf, cur, w1ih, w1hh,
                                                    g1bih, g1bhh, nxt);
    __hip_bfloat16* t = cur; cur = nxt; nxt = t;
  }
  readout_kernel<<<NB * RCH, 256, 0, stream>>>(cur, ebnd, r2w, r2b, out, HH);
}

// Round 7
// 716.135 us; speedup vs baseline: 1.1136x; 1.1136x over previous
//
#include <hip/hip_runtime.h>
#include <hip/hip_bf16.h>

#define NN 50000
#define NE 30000
#define NT 8
#define HH 128
#define NB 64
#define CONT 96
#define TPB 16
#define EDGES (NT * NE)
#define SBLK 512
#define SNB ((NN + SBLK - 1) / SBLK)   // 98
#define RCH 8                          // readout chunks per example
#define NTILE (NN / 16)                // 3125
#define GBLK ((NTILE + 3) / 4)         // 782 node-blocks in gru grid

typedef __attribute__((ext_vector_type(8))) short short8;
typedef __attribute__((ext_vector_type(4))) float f32x4;

__device__ __forceinline__ float sigm(float x) { return 1.f / (1.f + __expf(-x)); }
__device__ __forceinline__ unsigned short bfbits(float x) {
  __hip_bfloat16 b = __float2bfloat16(x);
  return *(unsigned short*)&b;
}

// ---------------------------------------------------------------- init (bf16 only)
__global__ __launch_bounds__(256) void init_kernel(
    const int* __restrict__ cid, const int* __restrict__ tg,
    const float* __restrict__ ctab, const float* __restrict__ ttab,
    __hip_bfloat16* __restrict__ sbf, __hip_bfloat16* __restrict__ ibf)
{
  int i = blockIdx.x * 256 + threadIdx.x;
  if (i >= NN * HH) return;
  int n = i >> 7, d = i & 127;
  float v;
  if (d < CONT) v = ctab[(size_t)cid[n] * CONT + d];
  else          v = ttab[(size_t)tg[n] * 32 + (d - CONT)];
  __hip_bfloat16 b = __float2bfloat16(v);
  sbf[i] = b;
  ibf[i] = b;
}

// ---------------------------------------------------------------- CSR build
__global__ __launch_bounds__(256) void hist_kernel(
    const int* __restrict__ etgt, int* __restrict__ cnt)
{
  int i = blockIdx.x * 256 + threadIdx.x;
  if (i >= EDGES) return;
  atomicAdd(&cnt[etgt[i]], 1);
}

__global__ __launch_bounds__(SBLK) void scanA_kernel(
    const int* __restrict__ cnt, int* __restrict__ row_ptr, int* __restrict__ bsum)
{
  __shared__ int sm[SBLK];
  const int tid = threadIdx.x;
  const int i = blockIdx.x * SBLK + tid;
  int v = (i < NN) ? cnt[i] : 0;
  sm[tid] = v;
  __syncthreads();
  for (int off = 1; off < SBLK; off <<= 1) {
    int t = (tid >= off) ? sm[tid - off] : 0;
    __syncthreads();
    sm[tid] += t;
    __syncthreads();
  }
  if (i < NN) row_ptr[i] = sm[tid] - v;
  if (tid == SBLK - 1) bsum[blockIdx.x] = sm[tid];
}

__global__ __launch_bounds__(128) void scanB_kernel(
    const int* __restrict__ bsum, int* __restrict__ boff, int* __restrict__ row_ptr)
{
  __shared__ int sm[128];
  const int tid = threadIdx.x;
  int v = (tid < SNB) ? bsum[tid] : 0;
  sm[tid] = v;
  __syncthreads();
  for (int off = 1; off < 128; off <<= 1) {
    int t = (tid >= off) ? sm[tid - off] : 0;
    __syncthreads();
    sm[tid] += t;
    __syncthreads();
  }
  if (tid < SNB) boff[tid] = sm[tid] - v;
  if (tid == 127) row_ptr[NN] = sm[127];
}

__global__ __launch_bounds__(SBLK) void scanC_kernel(
    int* __restrict__ row_ptr, int* __restrict__ cnt2, const int* __restrict__ boff)
{
  int i = blockIdx.x * SBLK + threadIdx.x;
  if (i >= NN) return;
  int r = row_ptr[i] + boff[blockIdx.x];
  row_ptr[i] = r;
  cnt2[i] = r;
}

__global__ __launch_bounds__(256) void scatter_kernel(
    const int* __restrict__ etgt, int* __restrict__ cnt2, int* __restrict__ perm)
{
  int i = blockIdx.x * 256 + threadIdx.x;
  if (i >= EDGES) return;
  perm[i] = atomicAdd(&cnt2[etgt[i]], 1);
}

__global__ __launch_bounds__(128) void exbound_kernel(
    const int* __restrict__ n2e, int* __restrict__ ebnd)
{
  int ex = threadIdx.x;
  if (ex > NB) return;
  int lo = 0, hi = NN;
  while (lo < hi) { int mid = (lo + hi) >> 1; if (n2e[mid] < ex) lo = mid + 1; else hi = mid; }
  ebnd[ex] = lo;
}

// ---------------------------------------------------------------- all weight swizzles
__device__ __forceinline__ void gru_swz_one(
    const float* __restrict__ W, __hip_bfloat16* __restrict__ out, int KSL, int mode, int i)
{
  int j = i & 7, lane = (i >> 3) & 63, kk = (i >> 9) % KSL, nt = i / (KSL * 512);
  int hi = lane >> 4, lo = lane & 15;
  int p = kk * 32 + hi * 8 + j;
  int k;
  if (mode == 0)      k = p;
  else if (mode == 1) k = (p & 7) * 16 + (p >> 3);
  else                k = (p < 128) ? p : 128 + ((p - 128) & 7) * 16 + ((p - 128) >> 3);
  out[i] = __float2bfloat16(W[(size_t)k * 384 + nt * 16 + lo]);
}

__global__ __launch_bounds__(256) void wswz_all_kernel(
    const float* __restrict__ msgW, __hip_bfloat16* __restrict__ wswz,
    const float* __restrict__ g0Wih, __hip_bfloat16* __restrict__ w0ih,
    const float* __restrict__ g0Whh, __hip_bfloat16* __restrict__ w0hh,
    const float* __restrict__ g1Wih, __hip_bfloat16* __restrict__ w1ih,
    const float* __restrict__ g1Whh, __hip_bfloat16* __restrict__ w1hh)
{
  int i = blockIdx.x * 256 + threadIdx.x;   // 507904 total
  if (i < 262144) {
    int j = i & 7, lane = (i >> 3) & 63, kk = (i >> 9) & 3, nt = (i >> 11) & 7, lt = i >> 14;
    int hi = lane >> 4, lo = lane & 15;
    int k = kk * 32 + hi * 8 + j;
    wswz[i] = __float2bfloat16(msgW[((size_t)lt * HH + k) * HH + nt * 16 + lo]);
    return;
  }
  i -= 262144;
  if (i < 49152)  { gru_swz_one(g0Wih, w0ih, 4, 1, i); return; }
  i -= 49152;
  if (i < 49152)  { gru_swz_one(g0Whh, w0hh, 4, 0, i); return; }
  i -= 49152;
  if (i < 98304)  { gru_swz_one(g1Wih, w1ih, 8, 2, i); return; }
  i -= 98304;
  if (i < 49152)  { gru_swz_one(g1Whh, w1hh, 4, 0, i); return; }
}

// ---------------------------------------------------------------- messages (MFMA)
__global__ __launch_bounds__(256) void msg_mfma_kernel(
    const __hip_bfloat16* __restrict__ sbf, const int* __restrict__ esrc,
    const int* __restrict__ perm, const __hip_bfloat16* __restrict__ wswz,
    const float* __restrict__ ball, __hip_bfloat16* __restrict__ msgs, int layer)
{
  __shared__ short8 Wl[8 * 4 * 64];  // 32KB
  const int t = blockIdx.y;
  {
    const float4* wg = (const float4*)(wswz + (size_t)(layer * NT + t) * 16384);
    float4* wl = (float4*)Wl;
    for (int i = threadIdx.x; i < 2048; i += 256) wl[i] = wg[i];
  }
  const int lane = threadIdx.x & 63;
  const int wv   = threadIdx.x >> 6;
  const int hi = lane >> 4, lo = lane & 15;
  float bias_v[8];
#pragma unroll
  for (int nt = 0; nt < 8; ++nt)
    bias_v[nt] = ball[(layer * NT + t) * HH + nt * 16 + lo];
  __syncthreads();

  const int tile_end = min((int)(blockIdx.x + 1) * TPB, NE / 16);
  for (int tile = blockIdx.x * TPB + wv; tile < tile_end; tile += 4) {
    const int e0 = tile * 16;
    const int src = esrc[t * NE + e0 + lo];
    const short* srow = (const short*)(sbf + (size_t)src * HH);
    short8 a[4];
#pragma unroll
    for (int kk = 0; kk < 4; ++kk)
      a[kk] = *(const short8*)(srow + kk * 32 + hi * 8);
    int slot[4];
#pragma unroll
    for (int r = 0; r < 4; ++r) slot[r] = perm[t * NE + e0 + hi * 4 + r];
    f32x4 acc[8];
#pragma unroll
    for (int nt = 0; nt < 8; ++nt) acc[nt] = (f32x4){0.f, 0.f, 0.f, 0.f};
#pragma unroll
    for (int nt = 0; nt < 8; ++nt)
#pragma unroll
      for (int kk = 0; kk < 4; ++kk)
        acc[nt] = __builtin_amdgcn_mfma_f32_16x16x32_bf16(
            a[kk], Wl[(nt * 4 + kk) * 64 + lane], acc[nt], 0, 0, 0);
#pragma unroll
    for (int r = 0; r < 4; ++r) {
      short8 m;
#pragma unroll
      for (int nt = 0; nt < 8; ++nt)
        ((unsigned short*)&m)[nt] = bfbits(acc[nt][r] + bias_v[nt]);
      *(short8*)((short*)msgs + (size_t)slot[r] * HH + lo * 8) = m;
    }
  }
}

// ---------------------------------------------------------------- reduce (CSR gather-sum)
__global__ __launch_bounds__(256) void reduce_kernel(
    const __hip_bfloat16* __restrict__ msgs, const int* __restrict__ row_ptr,
    __hip_bfloat16* __restrict__ agg)
{
  const int lane = threadIdx.x & 63;
  const int n = blockIdx.x * 4 + (threadIdx.x >> 6);
  if (n >= NN) return;
  const int b = row_ptr[n], e = row_ptr[n + 1];
  float a0 = 0.f, a1 = 0.f;
  for (int i = b; i < e; ++i) {
    unsigned int v = *(const unsigned int*)((const short*)msgs + (size_t)i * HH + lane * 2);
    a0 += __uint_as_float(v << 16);
    a1 += __uint_as_float(v & 0xffff0000u);
  }
  unsigned int o = ((unsigned int)bfbits(a1) << 16) | bfbits(a0);
  *(unsigned int*)((short*)agg + (size_t)n * HH + lane * 2) = o;
}

// ---------------------------------------------------------------- GRU (MFMA, dt-split grid)
// grid.x = 4 * GBLK: blockIdx.x / GBLK selects the dt-pair (gate-column slice),
// blockIdx.x % GBLK selects the node block. Different dt-groups write disjoint
// columns of sbf_out -> no race. Per-wave load chain ~56 instead of ~192.
template <int KSL>
__global__ __launch_bounds__(256) void gru_mfma_kernel(
    const __hip_bfloat16* __restrict__ agg,     // sigma order
    const __hip_bfloat16* __restrict__ ibf,     // row-major (layer1)
    const __hip_bfloat16* __restrict__ hbf,     // current state bf16 (read)
    const __hip_bfloat16* __restrict__ Wih_s,
    const __hip_bfloat16* __restrict__ Whh_s,
    const float* __restrict__ bih, const float* __restrict__ bhh,
    __hip_bfloat16* __restrict__ sbf_out)       // next state bf16 (write)
{
  const int lane = threadIdx.x & 63;
  const int wv   = threadIdx.x >> 6;
  const int dtg  = blockIdx.x / GBLK;          // 0..3
  const int tile = (blockIdx.x % GBLK) * 4 + wv;
  if (tile >= NTILE) return;
  const int nb = tile * 16;
  const int hi = lane >> 4, lo = lane & 15;

  short8 ax[KSL], ah[4];
  {
    const short* arow = (const short*)(agg + (size_t)(nb + lo) * HH);
    const short* hrow = (const short*)(hbf + (size_t)(nb + lo) * HH);
    if (KSL == 8) {
      const short* irow = (const short*)(ibf + (size_t)(nb + lo) * HH);
#pragma unroll
      for (int kk = 0; kk < 4; ++kk) {
        ax[kk]     = *(const short8*)(irow + kk * 32 + hi * 8);
        ax[kk + 4] = *(const short8*)(arow + kk * 32 + hi * 8);
      }
    } else {
#pragma unroll
      for (int kk = 0; kk < 4; ++kk)
        ax[kk] = *(const short8*)(arow + kk * 32 + hi * 8);
    }
#pragma unroll
    for (int kk = 0; kk < 4; ++kk)
      ah[kk] = *(const short8*)(hrow + kk * 32 + hi * 8);
  }

  const short8* __restrict__ Bih = (const short8*)Wih_s;
  const short8* __restrict__ Bhh = (const short8*)Whh_s;

#pragma unroll
  for (int d2 = 0; d2 < 2; ++d2) {
    const int dt = dtg * 2 + d2;
    f32x4 gi[3], gh[3];
#pragma unroll
    for (int g = 0; g < 3; ++g) {
      gi[g] = (f32x4){0.f, 0.f, 0.f, 0.f};
      gh[g] = (f32x4){0.f, 0.f, 0.f, 0.f};
    }
#pragma unroll
    for (int kk = 0; kk < KSL; ++kk)
#pragma unroll
      for (int g = 0; g < 3; ++g)
        gi[g] = __builtin_amdgcn_mfma_f32_16x16x32_bf16(
            ax[kk], Bih[((size_t)(dt + 8 * g) * KSL + kk) * 64 + lane], gi[g], 0, 0, 0);
#pragma unroll
    for (int kk = 0; kk < 4; ++kk)
#pragma unroll
      for (int g = 0; g < 3; ++g)
        gh[g] = __builtin_amdgcn_mfma_f32_16x16x32_bf16(
            ah[kk], Bhh[((size_t)(dt + 8 * g) * 4 + kk) * 64 + lane], gh[g], 0, 0, 0);
    const int c = dt * 16 + lo;
    const float bir = bih[c], biz = bih[c + 128], bin = bih[c + 256];
    const float bhr = bhh[c], bhz = bhh[c + 128], bhn = bhh[c + 256];
#pragma unroll
    for (int r = 0; r < 4; ++r) {
      const int node = nb + hi * 4 + r;
      const float rg = sigm(gi[0][r] + bir + gh[0][r] + bhr);
      const float zg = sigm(gi[1][r] + biz + gh[1][r] + bhz);
      const float ng = tanhf(gi[2][r] + bin + rg * (gh[2][r] + bhn));
      const float hc = __bfloat162float(hbf[(size_t)node * HH + c]);
      sbf_out[(size_t)node * HH + c] = __float2bfloat16((1.f - zg) * ng + zg * hc);
    }
  }
}

// ---------------------------------------------------------------- readout (bf16 input)
__global__ __launch_bounds__(256) void readout_kernel(
    const __hip_bfloat16* __restrict__ sbf, const int* __restrict__ ebnd,
    const float* __restrict__ rw, const float* __restrict__ rb,
    float* __restrict__ out, int coff)
{
  __shared__ float sm[4][128];
  const int ex = blockIdx.x / RCH, ch = blockIdx.x % RCH;
  const int s = ebnd[ex], e = ebnd[ex + 1];
  const int lane = threadIdx.x & 63;
  const int wv   = threadIdx.x >> 6;
  const float w0 = rw[2 * lane], w1 = rw[2 * lane + 1], rbv = rb[0];
  float a0 = 0.f, a1 = 0.f;
  for (int n = s + ch * 4 + wv; n < e; n += 4 * RCH) {
    unsigned int v = *(const unsigned int*)((const short*)sbf + (size_t)n * HH + lane * 2);
    const float s0 = __uint_as_float(v << 16);
    const float s1 = __uint_as_float(v & 0xffff0000u);
    float p = s0 * w0 + s1 * w1;
#pragma unroll
    for (int o = 32; o; o >>= 1) p += __shfl_xor(p, o, 64);
    const float g = sigm(p + rbv);
    a0 += g * s0;
    a1 += g * s1;
  }
  sm[wv][2 * lane] = a0;
  sm[wv][2 * lane + 1] = a1;
  __syncthreads();
  if (wv == 0) {
    const int c0 = 2 * lane, c1 = 2 * lane + 1;
    float v0 = sm[0][c0] + sm[1][c0] + sm[2][c0] + sm[3][c0];
    float v1 = sm[0][c1] + sm[1][c1] + sm[2][c1] + sm[3][c1];
    atomicAdd(&out[(size_t)ex * (2 * HH) + coff + c0], v0);
    atomicAdd(&out[(size_t)ex * (2 * HH) + coff + c1], v1);
  }
}

// ---------------------------------------------------------------- launch
extern "C" void kernel_launch(void* const* d_in, const int* in_sizes, int n_in,
                              void* d_out, int out_size, void* d_ws, size_t ws_size,
                              hipStream_t stream)
{
  const int*   cid   = (const int*)d_in[0];
  const int*   tg    = (const int*)d_in[1];
  const int*   esrc  = (const int*)d_in[2];
  const int*   etgt  = (const int*)d_in[3];
  const int*   n2e   = (const int*)d_in[4];
  const float* ctab  = (const float*)d_in[5];
  const float* ttab  = (const float*)d_in[6];
  const float* msgW  = (const float*)d_in[7];
  const float* msgb  = (const float*)d_in[8];
  const float* g0Wih = (const float*)d_in[9];
  const float* g0Whh = (const float*)d_in[10];
  const float* g0bih = (const float*)d_in[11];
  const float* g0bhh = (const float*)d_in[12];
  const float* g1Wih = (const float*)d_in[13];
  const float* g1Whh = (const float*)d_in[14];
  const float* g1bih = (const float*)d_in[15];
  const float* g1bhh = (const float*)d_in[16];
  const float* r1w   = (const float*)d_in[17];
  const float* r1b   = (const float*)d_in[18];
  const float* r2w   = (const float*)d_in[19];
  const float* r2b   = (const float*)d_in[20];

  float* out = (float*)d_out;
  __hip_bfloat16* sb0  = (__hip_bfloat16*)d_ws;
  __hip_bfloat16* sb1  = sb0 + (size_t)NN * HH;
  __hip_bfloat16* ibf  = sb1 + (size_t)NN * HH;
  __hip_bfloat16* agg  = ibf + (size_t)NN * HH;
  __hip_bfloat16* msgs = agg + (size_t)NN * HH;
  __hip_bfloat16* wswz = msgs + (size_t)EDGES * HH;
  __hip_bfloat16* w0ih = wswz + 262144;
  __hip_bfloat16* w0hh = w0ih + 24 * 4 * 512;
  __hip_bfloat16* w1ih = w0hh + 24 * 4 * 512;
  __hip_bfloat16* w1hh = w1ih + 24 * 8 * 512;
  int* row_ptr = (int*)(w1hh + 24 * 4 * 512);
  int* cnt     = row_ptr + NN + 1;
  int* cnt2    = cnt + NN;
  int* perm    = cnt2 + NN;
  int* bsum    = perm + EDGES;
  int* boff    = bsum + SNB;
  int* ebnd    = boff + SNB;

  hipMemsetAsync(d_out, 0, (size_t)NB * 2 * HH * sizeof(float), stream);
  hipMemsetAsync(cnt, 0, (size_t)NN * sizeof(int), stream);
  const int eblocks = (EDGES + 255) / 256;
  hist_kernel<<<eblocks, 256, 0, stream>>>(etgt, cnt);
  scanA_kernel<<<SNB, SBLK, 0, stream>>>(cnt, row_ptr, bsum);
  scanB_kernel<<<1, 128, 0, stream>>>(bsum, boff, row_ptr);
  scanC_kernel<<<SNB, SBLK, 0, stream>>>(row_ptr, cnt2, boff);
  scatter_kernel<<<eblocks, 256, 0, stream>>>(etgt, cnt2, perm);
  exbound_kernel<<<1, 128, 0, stream>>>(n2e, ebnd);

  wswz_all_kernel<<<507904 / 256, 256, 0, stream>>>(msgW, wswz, g0Wih, w0ih, g0Whh, w0hh,
                                                    g1Wih, w1ih, g1Whh, w1hh);
  init_kernel<<<(NN * HH + 255) / 256, 256, 0, stream>>>(cid, tg, ctab, ttab, sb0, ibf);

  dim3 mgrid((NE / 16 + TPB - 1) / TPB, NT);
  const int rblocks = (NN + 3) / 4;
  __hip_bfloat16* cur = sb0;
  __hip_bfloat16* nxt = sb1;
  for (int s = 0; s < 3; ++s) {
    msg_mfma_kernel<<<mgrid, 256, 0, stream>>>(cur, esrc, perm, wswz, msgb, msgs, 0);
    reduce_kernel<<<rblocks, 256, 0, stream>>>(msgs, row_ptr, agg);
    gru_mfma_kernel<4><<<4 * GBLK, 256, 0, stream>>>(agg, ibf, cur, w0ih, w0hh,
                                                     g0bih, g0bhh, nxt);
    __hip_bfloat16* t = cur; cur = nxt; nxt = t;
  }
  readout_kernel<<<NB * RCH, 256, 0, stream>>>(cur, ebnd, r1w, r1b, out, 0);

  for (int s = 0; s < 3; ++s) {
    msg_mfma_kernel<<<mgrid, 256, 0, stream>>>(cur, esrc, perm, wswz, msgb, msgs, 1);
    reduce_kernel<<<rblocks, 256, 0, stream>>>(msgs, row_ptr, agg);
    gru_mfma_kernel<8><<<4 * GBLK, 256, 0, stream>>>(agg, ibf, cur, w1ih, w1hh,
                                                     g1bih, g1bhh, nxt);
    __hip_bfloat16* t = cur; cur = nxt; nxt = t;
  }
  readout_kernel<<<NB * RCH, 256, 0, stream>>>(cur, ebnd, r2w, r2b, out, HH);
}

// Round 8
// 644.541 us; speedup vs baseline: 1.2373x; 1.1111x over previous
//
#include <hip/hip_runtime.h>
#include <hip/hip_bf16.h>

#define NN 50000
#define NE 30000
#define NT 8
#define HH 128
#define NB 64
#define CONT 96
#define TPB 16
#define EDGES (NT * NE)
#define SBLK 512
#define SNB ((NN + SBLK - 1) / SBLK)   // 98
#define RCH 8                          // readout chunks per example
#define NTILE (NN / 16)                // 3125
#define NPAIR ((NTILE + 1) / 2)        // 1563

typedef __attribute__((ext_vector_type(8))) short short8;
typedef __attribute__((ext_vector_type(4))) float f32x4;

__device__ __forceinline__ float sigm(float x) { return 1.f / (1.f + __expf(-x)); }
__device__ __forceinline__ unsigned short bfbits(float x) {
  __hip_bfloat16 b = __float2bfloat16(x);
  return *(unsigned short*)&b;
}

// ---------------------------------------------------------------- init (bf16 only)
__global__ __launch_bounds__(256) void init_kernel(
    const int* __restrict__ cid, const int* __restrict__ tg,
    const float* __restrict__ ctab, const float* __restrict__ ttab,
    __hip_bfloat16* __restrict__ sbf, __hip_bfloat16* __restrict__ ibf)
{
  int i = blockIdx.x * 256 + threadIdx.x;
  if (i >= NN * HH) return;
  int n = i >> 7, d = i & 127;
  float v;
  if (d < CONT) v = ctab[(size_t)cid[n] * CONT + d];
  else          v = ttab[(size_t)tg[n] * 32 + (d - CONT)];
  __hip_bfloat16 b = __float2bfloat16(v);
  sbf[i] = b;
  ibf[i] = b;
}

// ---------------------------------------------------------------- CSR build
__global__ __launch_bounds__(256) void hist_kernel(
    const int* __restrict__ etgt, int* __restrict__ cnt)
{
  int i = blockIdx.x * 256 + threadIdx.x;
  if (i >= EDGES) return;
  atomicAdd(&cnt[etgt[i]], 1);
}

__global__ __launch_bounds__(SBLK) void scanA_kernel(
    const int* __restrict__ cnt, int* __restrict__ row_ptr, int* __restrict__ bsum)
{
  __shared__ int sm[SBLK];
  const int tid = threadIdx.x;
  const int i = blockIdx.x * SBLK + tid;
  int v = (i < NN) ? cnt[i] : 0;
  sm[tid] = v;
  __syncthreads();
  for (int off = 1; off < SBLK; off <<= 1) {
    int t = (tid >= off) ? sm[tid - off] : 0;
    __syncthreads();
    sm[tid] += t;
    __syncthreads();
  }
  if (i < NN) row_ptr[i] = sm[tid] - v;
  if (tid == SBLK - 1) bsum[blockIdx.x] = sm[tid];
}

__global__ __launch_bounds__(128) void scanB_kernel(
    const int* __restrict__ bsum, int* __restrict__ boff, int* __restrict__ row_ptr)
{
  __shared__ int sm[128];
  const int tid = threadIdx.x;
  int v = (tid < SNB) ? bsum[tid] : 0;
  sm[tid] = v;
  __syncthreads();
  for (int off = 1; off < 128; off <<= 1) {
    int t = (tid >= off) ? sm[tid - off] : 0;
    __syncthreads();
    sm[tid] += t;
    __syncthreads();
  }
  if (tid < SNB) boff[tid] = sm[tid] - v;
  if (tid == 127) row_ptr[NN] = sm[127];
}

__global__ __launch_bounds__(SBLK) void scanC_kernel(
    int* __restrict__ row_ptr, int* __restrict__ cnt2, const int* __restrict__ boff)
{
  int i = blockIdx.x * SBLK + threadIdx.x;
  if (i >= NN) return;
  int r = row_ptr[i] + boff[blockIdx.x];
  row_ptr[i] = r;
  cnt2[i] = r;
}

__global__ __launch_bounds__(256) void scatter_kernel(
    const int* __restrict__ etgt, int* __restrict__ cnt2, int* __restrict__ perm)
{
  int i = blockIdx.x * 256 + threadIdx.x;
  if (i >= EDGES) return;
  perm[i] = atomicAdd(&cnt2[etgt[i]], 1);
}

__global__ __launch_bounds__(128) void exbound_kernel(
    const int* __restrict__ n2e, int* __restrict__ ebnd)
{
  int ex = threadIdx.x;
  if (ex > NB) return;
  int lo = 0, hi = NN;
  while (lo < hi) { int mid = (lo + hi) >> 1; if (n2e[mid] < ex) lo = mid + 1; else hi = mid; }
  ebnd[ex] = lo;
}

// ---------------------------------------------------------------- all weight swizzles
__device__ __forceinline__ void gru_swz_one(
    const float* __restrict__ W, __hip_bfloat16* __restrict__ out, int KSL, int mode, int i)
{
  int j = i & 7, lane = (i >> 3) & 63, kk = (i >> 9) % KSL, nt = i / (KSL * 512);
  int hi = lane >> 4, lo = lane & 15;
  int p = kk * 32 + hi * 8 + j;
  int k;
  if (mode == 0)      k = p;
  else if (mode == 1) k = (p & 7) * 16 + (p >> 3);
  else                k = (p < 128) ? p : 128 + ((p - 128) & 7) * 16 + ((p - 128) >> 3);
  out[i] = __float2bfloat16(W[(size_t)k * 384 + nt * 16 + lo]);
}

__global__ __launch_bounds__(256) void wswz_all_kernel(
    const float* __restrict__ msgW, __hip_bfloat16* __restrict__ wswz,
    const float* __restrict__ g0Wih, __hip_bfloat16* __restrict__ w0ih,
    const float* __restrict__ g0Whh, __hip_bfloat16* __restrict__ w0hh,
    const float* __restrict__ g1Wih, __hip_bfloat16* __restrict__ w1ih,
    const float* __restrict__ g1Whh, __hip_bfloat16* __restrict__ w1hh)
{
  int i = blockIdx.x * 256 + threadIdx.x;   // 507904 total
  if (i < 262144) {
    int j = i & 7, lane = (i >> 3) & 63, kk = (i >> 9) & 3, nt = (i >> 11) & 7, lt = i >> 14;
    int hi = lane >> 4, lo = lane & 15;
    int k = kk * 32 + hi * 8 + j;
    wswz[i] = __float2bfloat16(msgW[((size_t)lt * HH + k) * HH + nt * 16 + lo]);
    return;
  }
  i -= 262144;
  if (i < 49152)  { gru_swz_one(g0Wih, w0ih, 4, 1, i); return; }
  i -= 49152;
  if (i < 49152)  { gru_swz_one(g0Whh, w0hh, 4, 0, i); return; }
  i -= 49152;
  if (i < 98304)  { gru_swz_one(g1Wih, w1ih, 8, 2, i); return; }
  i -= 98304;
  if (i < 49152)  { gru_swz_one(g1Whh, w1hh, 4, 0, i); return; }
}

// ---------------------------------------------------------------- messages (MFMA)
__global__ __launch_bounds__(256) void msg_mfma_kernel(
    const __hip_bfloat16* __restrict__ sbf, const int* __restrict__ esrc,
    const int* __restrict__ perm, const __hip_bfloat16* __restrict__ wswz,
    const float* __restrict__ ball, __hip_bfloat16* __restrict__ msgs, int layer)
{
  __shared__ short8 Wl[8 * 4 * 64];  // 32KB
  const int t = blockIdx.y;
  {
    const float4* wg = (const float4*)(wswz + (size_t)(layer * NT + t) * 16384);
    float4* wl = (float4*)Wl;
    for (int i = threadIdx.x; i < 2048; i += 256) wl[i] = wg[i];
  }
  const int lane = threadIdx.x & 63;
  const int wv   = threadIdx.x >> 6;
  const int hi = lane >> 4, lo = lane & 15;
  float bias_v[8];
#pragma unroll
  for (int nt = 0; nt < 8; ++nt)
    bias_v[nt] = ball[(layer * NT + t) * HH + nt * 16 + lo];
  __syncthreads();

  const int tile_end = min((int)(blockIdx.x + 1) * TPB, NE / 16);
  for (int tile = blockIdx.x * TPB + wv; tile < tile_end; tile += 4) {
    const int e0 = tile * 16;
    const int src = esrc[t * NE + e0 + lo];
    const short* srow = (const short*)(sbf + (size_t)src * HH);
    short8 a[4];
#pragma unroll
    for (int kk = 0; kk < 4; ++kk)
      a[kk] = *(const short8*)(srow + kk * 32 + hi * 8);
    int slot[4];
#pragma unroll
    for (int r = 0; r < 4; ++r) slot[r] = perm[t * NE + e0 + hi * 4 + r];
    f32x4 acc[8];
#pragma unroll
    for (int nt = 0; nt < 8; ++nt) acc[nt] = (f32x4){0.f, 0.f, 0.f, 0.f};
#pragma unroll
    for (int nt = 0; nt < 8; ++nt)
#pragma unroll
      for (int kk = 0; kk < 4; ++kk)
        acc[nt] = __builtin_amdgcn_mfma_f32_16x16x32_bf16(
            a[kk], Wl[(nt * 4 + kk) * 64 + lane], acc[nt], 0, 0, 0);
#pragma unroll
    for (int r = 0; r < 4; ++r) {
      short8 m;
#pragma unroll
      for (int nt = 0; nt < 8; ++nt)
        ((unsigned short*)&m)[nt] = bfbits(acc[nt][r] + bias_v[nt]);
      *(short8*)((short*)msgs + (size_t)slot[r] * HH + lo * 8) = m;
    }
  }
}

// ---------------------------------------------------------------- reduce (CSR gather-sum)
__global__ __launch_bounds__(256) void reduce_kernel(
    const __hip_bfloat16* __restrict__ msgs, const int* __restrict__ row_ptr,
    __hip_bfloat16* __restrict__ agg)
{
  const int lane = threadIdx.x & 63;
  const int n = blockIdx.x * 4 + (threadIdx.x >> 6);
  if (n >= NN) return;
  const int b = row_ptr[n], e = row_ptr[n + 1];
  float a0 = 0.f, a1 = 0.f;
  for (int i = b; i < e; ++i) {
    unsigned int v = *(const unsigned int*)((const short*)msgs + (size_t)i * HH + lane * 2);
    a0 += __uint_as_float(v << 16);
    a1 += __uint_as_float(v & 0xffff0000u);
  }
  unsigned int o = ((unsigned int)bfbits(a1) << 16) | bfbits(a0);
  *(unsigned int*)((short*)agg + (size_t)n * HH + lane * 2) = o;
}

// ---------------------------------------------------------------- GRU (MFMA, LDS-staged B, 2 tiles/wave)
// grid = (ceil(NPAIR/4), 4 dtg). Block stages its dt-pair's ih+hh fragments
// into LDS once (48/72 KB); wave wv computes node-tile pair blockIdx.x*4+wv.
// r/z accumulators merged across ih/hh paths (reference sums them anyway).
template <int KSL>
__global__ __launch_bounds__(256) void gru_mfma_kernel(
    const __hip_bfloat16* __restrict__ agg,     // sigma order
    const __hip_bfloat16* __restrict__ ibf,     // row-major (layer1)
    const __hip_bfloat16* __restrict__ hbf,     // current state bf16 (read)
    const __hip_bfloat16* __restrict__ Wih_s,
    const __hip_bfloat16* __restrict__ Whh_s,
    const float* __restrict__ bih, const float* __restrict__ bhh,
    __hip_bfloat16* __restrict__ sbf_out)       // next state bf16 (write)
{
  __shared__ short8 BihL[2 * 3 * KSL * 64];
  __shared__ short8 BhhL[2 * 3 * 4 * 64];
  const int dtg = blockIdx.y;                  // 0..3
  {
    const short8* Bih_g = (const short8*)Wih_s;
    const short8* Bhh_g = (const short8*)Whh_s;
    for (int i = threadIdx.x; i < 2 * 3 * KSL * 64; i += 256) {
      int lane_i = i & 63, kk = (i >> 6) % KSL, g = ((i >> 6) / KSL) % 3, d2 = (i >> 6) / (KSL * 3);
      BihL[i] = Bih_g[((size_t)(dtg * 2 + d2 + 8 * g) * KSL + kk) * 64 + lane_i];
    }
    for (int i = threadIdx.x; i < 2 * 3 * 4 * 64; i += 256) {
      int lane_i = i & 63, kk = (i >> 6) & 3, g = ((i >> 6) >> 2) % 3, d2 = (i >> 6) / 12;
      BhhL[i] = Bhh_g[((size_t)(dtg * 2 + d2 + 8 * g) * 4 + kk) * 64 + lane_i];
    }
  }
  const int lane = threadIdx.x & 63;
  const int wv   = threadIdx.x >> 6;
  const int hi = lane >> 4, lo = lane & 15;
  float birv[2], bizv[2], binv[2], bhrv[2], bhzv[2], bhnv[2];
#pragma unroll
  for (int d2 = 0; d2 < 2; ++d2) {
    const int c = (dtg * 2 + d2) * 16 + lo;
    birv[d2] = bih[c]; bizv[d2] = bih[c + 128]; binv[d2] = bih[c + 256];
    bhrv[d2] = bhh[c]; bhzv[d2] = bhh[c + 128]; bhnv[d2] = bhh[c + 256];
  }
  __syncthreads();

  const int pt = blockIdx.x * 4 + wv;
  if (pt >= NPAIR) return;
  const int t0 = pt * 2;
  const bool two = (t0 + 1 < NTILE);

  short8 ax[2][KSL], ah[2][4];
#pragma unroll
  for (int u = 0; u < 2; ++u) {
    const int nb = ((u && two) ? t0 + 1 : t0) * 16;
    const short* arow = (const short*)(agg + (size_t)(nb + lo) * HH);
    const short* hrow = (const short*)(hbf + (size_t)(nb + lo) * HH);
    if (KSL == 8) {
      const short* irow = (const short*)(ibf + (size_t)(nb + lo) * HH);
#pragma unroll
      for (int kk = 0; kk < 4; ++kk) {
        ax[u][kk]     = *(const short8*)(irow + kk * 32 + hi * 8);
        ax[u][kk + 4] = *(const short8*)(arow + kk * 32 + hi * 8);
      }
    } else {
#pragma unroll
      for (int kk = 0; kk < KSL; ++kk)
        ax[u][kk] = *(const short8*)(arow + kk * 32 + hi * 8);
    }
#pragma unroll
    for (int kk = 0; kk < 4; ++kk)
      ah[u][kk] = *(const short8*)(hrow + kk * 32 + hi * 8);
  }

  f32x4 aR[2][2], aZ[2][2], aNi[2][2], aNh[2][2];   // [d2][tile]
#pragma unroll
  for (int d2 = 0; d2 < 2; ++d2)
#pragma unroll
    for (int u = 0; u < 2; ++u) {
      aR[d2][u] = (f32x4){0.f, 0.f, 0.f, 0.f};
      aZ[d2][u] = (f32x4){0.f, 0.f, 0.f, 0.f};
      aNi[d2][u] = (f32x4){0.f, 0.f, 0.f, 0.f};
      aNh[d2][u] = (f32x4){0.f, 0.f, 0.f, 0.f};
    }

#pragma unroll
  for (int d2 = 0; d2 < 2; ++d2) {
#pragma unroll
    for (int kk = 0; kk < KSL; ++kk) {
      short8 br = BihL[((d2 * 3 + 0) * KSL + kk) * 64 + lane];
      short8 bz = BihL[((d2 * 3 + 1) * KSL + kk) * 64 + lane];
      short8 bn = BihL[((d2 * 3 + 2) * KSL + kk) * 64 + lane];
#pragma unroll
      for (int u = 0; u < 2; ++u) {
        aR[d2][u]  = __builtin_amdgcn_mfma_f32_16x16x32_bf16(ax[u][kk], br, aR[d2][u], 0, 0, 0);
        aZ[d2][u]  = __builtin_amdgcn_mfma_f32_16x16x32_bf16(ax[u][kk], bz, aZ[d2][u], 0, 0, 0);
        aNi[d2][u] = __builtin_amdgcn_mfma_f32_16x16x32_bf16(ax[u][kk], bn, aNi[d2][u], 0, 0, 0);
      }
    }
#pragma unroll
    for (int kk = 0; kk < 4; ++kk) {
      short8 br = BhhL[((d2 * 3 + 0) * 4 + kk) * 64 + lane];
      short8 bz = BhhL[((d2 * 3 + 1) * 4 + kk) * 64 + lane];
      short8 bn = BhhL[((d2 * 3 + 2) * 4 + kk) * 64 + lane];
#pragma unroll
      for (int u = 0; u < 2; ++u) {
        aR[d2][u]  = __builtin_amdgcn_mfma_f32_16x16x32_bf16(ah[u][kk], br, aR[d2][u], 0, 0, 0);
        aZ[d2][u]  = __builtin_amdgcn_mfma_f32_16x16x32_bf16(ah[u][kk], bz, aZ[d2][u], 0, 0, 0);
        aNh[d2][u] = __builtin_amdgcn_mfma_f32_16x16x32_bf16(ah[u][kk], bn, aNh[d2][u], 0, 0, 0);
      }
    }
  }

  const int uend = two ? 2 : 1;
  for (int u = 0; u < uend; ++u) {
    const int nb = (t0 + u) * 16;
#pragma unroll
    for (int d2 = 0; d2 < 2; ++d2) {
      const int c = (dtg * 2 + d2) * 16 + lo;
#pragma unroll
      for (int r = 0; r < 4; ++r) {
        const int node = nb + hi * 4 + r;
        const float rg = sigm(aR[d2][u][r] + birv[d2] + bhrv[d2]);
        const float zg = sigm(aZ[d2][u][r] + bizv[d2] + bhzv[d2]);
        const float ng = tanhf(aNi[d2][u][r] + binv[d2] + rg * (aNh[d2][u][r] + bhnv[d2]));
        const float hc = __bfloat162float(hbf[(size_t)node * HH + c]);
        sbf_out[(size_t)node * HH + c] = __float2bfloat16((1.f - zg) * ng + zg * hc);
      }
    }
  }
}

// ---------------------------------------------------------------- readout (bf16 input)
__global__ __launch_bounds__(256) void readout_kernel(
    const __hip_bfloat16* __restrict__ sbf, const int* __restrict__ ebnd,
    const float* __restrict__ rw, const float* __restrict__ rb,
    float* __restrict__ out, int coff)
{
  __shared__ float sm[4][128];
  const int ex = blockIdx.x / RCH, ch = blockIdx.x % RCH;
  const int s = ebnd[ex], e = ebnd[ex + 1];
  const int lane = threadIdx.x & 63;
  const int wv   = threadIdx.x >> 6;
  const float w0 = rw[2 * lane], w1 = rw[2 * lane + 1], rbv = rb[0];
  float a0 = 0.f, a1 = 0.f;
  for (int n = s + ch * 4 + wv; n < e; n += 4 * RCH) {
    unsigned int v = *(const unsigned int*)((const short*)sbf + (size_t)n * HH + lane * 2);
    const float s0 = __uint_as_float(v << 16);
    const float s1 = __uint_as_float(v & 0xffff0000u);
    float p = s0 * w0 + s1 * w1;
#pragma unroll
    for (int o = 32; o; o >>= 1) p += __shfl_xor(p, o, 64);
    const float g = sigm(p + rbv);
    a0 += g * s0;
    a1 += g * s1;
  }
  sm[wv][2 * lane] = a0;
  sm[wv][2 * lane + 1] = a1;
  __syncthreads();
  if (wv == 0) {
    const int c0 = 2 * lane, c1 = 2 * lane + 1;
    float v0 = sm[0][c0] + sm[1][c0] + sm[2][c0] + sm[3][c0];
    float v1 = sm[0][c1] + sm[1][c1] + sm[2][c1] + sm[3][c1];
    atomicAdd(&out[(size_t)ex * (2 * HH) + coff + c0], v0);
    atomicAdd(&out[(size_t)ex * (2 * HH) + coff + c1], v1);
  }
}

// ---------------------------------------------------------------- launch
extern "C" void kernel_launch(void* const* d_in, const int* in_sizes, int n_in,
                              void* d_out, int out_size, void* d_ws, size_t ws_size,
                              hipStream_t stream)
{
  const int*   cid   = (const int*)d_in[0];
  const int*   tg    = (const int*)d_in[1];
  const int*   esrc  = (const int*)d_in[2];
  const int*   etgt  = (const int*)d_in[3];
  const int*   n2e   = (const int*)d_in[4];
  const float* ctab  = (const float*)d_in[5];
  const float* ttab  = (const float*)d_in[6];
  const float* msgW  = (const float*)d_in[7];
  const float* msgb  = (const float*)d_in[8];
  const float* g0Wih = (const float*)d_in[9];
  const float* g0Whh = (const float*)d_in[10];
  const float* g0bih = (const float*)d_in[11];
  const float* g0bhh = (const float*)d_in[12];
  const float* g1Wih = (const float*)d_in[13];
  const float* g1Whh = (const float*)d_in[14];
  const float* g1bih = (const float*)d_in[15];
  const float* g1bhh = (const float*)d_in[16];
  const float* r1w   = (const float*)d_in[17];
  const float* r1b   = (const float*)d_in[18];
  const float* r2w   = (const float*)d_in[19];
  const float* r2b   = (const float*)d_in[20];

  float* out = (float*)d_out;
  __hip_bfloat16* sb0  = (__hip_bfloat16*)d_ws;
  __hip_bfloat16* sb1  = sb0 + (size_t)NN * HH;
  __hip_bfloat16* ibf  = sb1 + (size_t)NN * HH;
  __hip_bfloat16* agg  = ibf + (size_t)NN * HH;
  __hip_bfloat16* msgs = agg + (size_t)NN * HH;
  __hip_bfloat16* wswz = msgs + (size_t)EDGES * HH;
  __hip_bfloat16* w0ih = wswz + 262144;
  __hip_bfloat16* w0hh = w0ih + 24 * 4 * 512;
  __hip_bfloat16* w1ih = w0hh + 24 * 4 * 512;
  __hip_bfloat16* w1hh = w1ih + 24 * 8 * 512;
  int* row_ptr = (int*)(w1hh + 24 * 4 * 512);
  int* cnt     = row_ptr + NN + 1;
  int* cnt2    = cnt + NN;
  int* perm    = cnt2 + NN;
  int* bsum    = perm + EDGES;
  int* boff    = bsum + SNB;
  int* ebnd    = boff + SNB;

  hipMemsetAsync(d_out, 0, (size_t)NB * 2 * HH * sizeof(float), stream);
  hipMemsetAsync(cnt, 0, (size_t)NN * sizeof(int), stream);
  const int eblocks = (EDGES + 255) / 256;
  hist_kernel<<<eblocks, 256, 0, stream>>>(etgt, cnt);
  scanA_kernel<<<SNB, SBLK, 0, stream>>>(cnt, row_ptr, bsum);
  scanB_kernel<<<1, 128, 0, stream>>>(bsum, boff, row_ptr);
  scanC_kernel<<<SNB, SBLK, 0, stream>>>(row_ptr, cnt2, boff);
  scatter_kernel<<<eblocks, 256, 0, stream>>>(etgt, cnt2, perm);
  exbound_kernel<<<1, 128, 0, stream>>>(n2e, ebnd);

  wswz_all_kernel<<<507904 / 256, 256, 0, stream>>>(msgW, wswz, g0Wih, w0ih, g0Whh, w0hh,
                                                    g1Wih, w1ih, g1Whh, w1hh);
  init_kernel<<<(NN * HH + 255) / 256, 256, 0, stream>>>(cid, tg, ctab, ttab, sb0, ibf);

  dim3 mgrid((NE / 16 + TPB - 1) / TPB, NT);
  dim3 ggrid((NPAIR + 3) / 4, 4);
  const int rblocks = (NN + 3) / 4;
  __hip_bfloat16* cur = sb0;
  __hip_bfloat16* nxt = sb1;
  for (int s = 0; s < 3; ++s) {
    msg_mfma_kernel<<<mgrid, 256, 0, stream>>>(cur, esrc, perm, wswz, msgb, msgs, 0);
    reduce_kernel<<<rblocks, 256, 0, stream>>>(msgs, row_ptr, agg);
    gru_mfma_kernel<4><<<ggrid, 256, 0, stream>>>(agg, ibf, cur, w0ih, w0hh,
                                                  g0bih, g0bhh, nxt);
    __hip_bfloat16* t = cur; cur = nxt; nxt = t;
  }
  readout_kernel<<<NB * RCH, 256, 0, stream>>>(cur, ebnd, r1w, r1b, out, 0);

  for (int s = 0; s < 3; ++s) {
    msg_mfma_kernel<<<mgrid, 256, 0, stream>>>(cur, esrc, perm, wswz, msgb, msgs, 1);
    reduce_kernel<<<rblocks, 256, 0, stream>>>(msgs, row_ptr, agg);
    gru_mfma_kernel<8><<<ggrid, 256, 0, stream>>>(agg, ibf, cur, w1ih, w1hh,
                                                  g1bih, g1bhh, nxt);
    __hip_bfloat16* t = cur; cur = nxt; nxt = t;
  }
  readout_kernel<<<NB * RCH, 256, 0, stream>>>(cur, ebnd, r2w, r2b, out, HH);
}

// Round 9
// 591.165 us; speedup vs baseline: 1.3490x; 1.0903x over previous
//
#include <hip/hip_runtime.h>
#include <hip/hip_bf16.h>

#define NN 50000
#define NE 30000
#define NT 8
#define HH 128
#define NB 64
#define CONT 96
#define TPB 16
#define EDGES (NT * NE)
#define SBLK 512
#define SNB ((NN + SBLK - 1) / SBLK)   // 98
#define RCH 8                          // readout chunks per example
#define NTILE (NN / 16)                // 3125
#define NPAIR ((NTILE + 1) / 2)        // 1563
#define XB ((NPAIR + 3) / 4)           // 391 node-chunks (4 pairs each)
#define GGRID ((((XB + 7) / 8)) * 32)  // 1568 swizzled blocks

typedef __attribute__((ext_vector_type(8))) short short8;
typedef __attribute__((ext_vector_type(4))) float f32x4;

__device__ __forceinline__ float sigm(float x) { return 1.f / (1.f + __expf(-x)); }
__device__ __forceinline__ float tanhf_fast(float x) {
  float e = __expf(2.f * x);           // saturates correctly: inf -> 1, 0 -> -1
  return 1.f - 2.f / (e + 1.f);
}
__device__ __forceinline__ unsigned short bfbits(float x) {
  __hip_bfloat16 b = __float2bfloat16(x);
  return *(unsigned short*)&b;
}

// ---------------------------------------------------------------- init (bf16 only)
__global__ __launch_bounds__(256) void init_kernel(
    const int* __restrict__ cid, const int* __restrict__ tg,
    const float* __restrict__ ctab, const float* __restrict__ ttab,
    __hip_bfloat16* __restrict__ sbf, __hip_bfloat16* __restrict__ ibf)
{
  int i = blockIdx.x * 256 + threadIdx.x;
  if (i >= NN * HH) return;
  int n = i >> 7, d = i & 127;
  float v;
  if (d < CONT) v = ctab[(size_t)cid[n] * CONT + d];
  else          v = ttab[(size_t)tg[n] * 32 + (d - CONT)];
  __hip_bfloat16 b = __float2bfloat16(v);
  sbf[i] = b;
  ibf[i] = b;
}

// ---------------------------------------------------------------- CSR build
__global__ __launch_bounds__(256) void hist_kernel(
    const int* __restrict__ etgt, int* __restrict__ cnt)
{
  int i = blockIdx.x * 256 + threadIdx.x;
  if (i >= EDGES) return;
  atomicAdd(&cnt[etgt[i]], 1);
}

__global__ __launch_bounds__(SBLK) void scanA_kernel(
    const int* __restrict__ cnt, int* __restrict__ row_ptr, int* __restrict__ bsum)
{
  __shared__ int sm[SBLK];
  const int tid = threadIdx.x;
  const int i = blockIdx.x * SBLK + tid;
  int v = (i < NN) ? cnt[i] : 0;
  sm[tid] = v;
  __syncthreads();
  for (int off = 1; off < SBLK; off <<= 1) {
    int t = (tid >= off) ? sm[tid - off] : 0;
    __syncthreads();
    sm[tid] += t;
    __syncthreads();
  }
  if (i < NN) row_ptr[i] = sm[tid] - v;
  if (tid == SBLK - 1) bsum[blockIdx.x] = sm[tid];
}

__global__ __launch_bounds__(128) void scanB_kernel(
    const int* __restrict__ bsum, int* __restrict__ boff, int* __restrict__ row_ptr)
{
  __shared__ int sm[128];
  const int tid = threadIdx.x;
  int v = (tid < SNB) ? bsum[tid] : 0;
  sm[tid] = v;
  __syncthreads();
  for (int off = 1; off < 128; off <<= 1) {
    int t = (tid >= off) ? sm[tid - off] : 0;
    __syncthreads();
    sm[tid] += t;
    __syncthreads();
  }
  if (tid < SNB) boff[tid] = sm[tid] - v;
  if (tid == 127) row_ptr[NN] = sm[127];
}

__global__ __launch_bounds__(SBLK) void scanC_kernel(
    int* __restrict__ row_ptr, int* __restrict__ cnt2, const int* __restrict__ boff)
{
  int i = blockIdx.x * SBLK + threadIdx.x;
  if (i >= NN) return;
  int r = row_ptr[i] + boff[blockIdx.x];
  row_ptr[i] = r;
  cnt2[i] = r;
}

__global__ __launch_bounds__(256) void scatter_kernel(
    const int* __restrict__ etgt, int* __restrict__ cnt2, int* __restrict__ perm)
{
  int i = blockIdx.x * 256 + threadIdx.x;
  if (i >= EDGES) return;
  perm[i] = atomicAdd(&cnt2[etgt[i]], 1);
}

__global__ __launch_bounds__(128) void exbound_kernel(
    const int* __restrict__ n2e, int* __restrict__ ebnd)
{
  int ex = threadIdx.x;
  if (ex > NB) return;
  int lo = 0, hi = NN;
  while (lo < hi) { int mid = (lo + hi) >> 1; if (n2e[mid] < ex) lo = mid + 1; else hi = mid; }
  ebnd[ex] = lo;
}

// ---------------------------------------------------------------- all weight swizzles
__device__ __forceinline__ void gru_swz_one(
    const float* __restrict__ W, __hip_bfloat16* __restrict__ out, int KSL, int mode, int i)
{
  int j = i & 7, lane = (i >> 3) & 63, kk = (i >> 9) % KSL, nt = i / (KSL * 512);
  int hi = lane >> 4, lo = lane & 15;
  int p = kk * 32 + hi * 8 + j;
  int k;
  if (mode == 0)      k = p;
  else if (mode == 1) k = (p & 7) * 16 + (p >> 3);
  else                k = (p < 128) ? p : 128 + ((p - 128) & 7) * 16 + ((p - 128) >> 3);
  out[i] = __float2bfloat16(W[(size_t)k * 384 + nt * 16 + lo]);
}

__global__ __launch_bounds__(256) void wswz_all_kernel(
    const float* __restrict__ msgW, __hip_bfloat16* __restrict__ wswz,
    const float* __restrict__ g0Wih, __hip_bfloat16* __restrict__ w0ih,
    const float* __restrict__ g0Whh, __hip_bfloat16* __restrict__ w0hh,
    const float* __restrict__ g1Wih, __hip_bfloat16* __restrict__ w1ih,
    const float* __restrict__ g1Whh, __hip_bfloat16* __restrict__ w1hh)
{
  int i = blockIdx.x * 256 + threadIdx.x;   // 507904 total
  if (i < 262144) {
    int j = i & 7, lane = (i >> 3) & 63, kk = (i >> 9) & 3, nt = (i >> 11) & 7, lt = i >> 14;
    int hi = lane >> 4, lo = lane & 15;
    int k = kk * 32 + hi * 8 + j;
    wswz[i] = __float2bfloat16(msgW[((size_t)lt * HH + k) * HH + nt * 16 + lo]);
    return;
  }
  i -= 262144;
  if (i < 49152)  { gru_swz_one(g0Wih, w0ih, 4, 1, i); return; }
  i -= 49152;
  if (i < 49152)  { gru_swz_one(g0Whh, w0hh, 4, 0, i); return; }
  i -= 49152;
  if (i < 98304)  { gru_swz_one(g1Wih, w1ih, 8, 2, i); return; }
  i -= 98304;
  if (i < 49152)  { gru_swz_one(g1Whh, w1hh, 4, 0, i); return; }
}

// ---------------------------------------------------------------- messages (MFMA)
__global__ __launch_bounds__(256) void msg_mfma_kernel(
    const __hip_bfloat16* __restrict__ sbf, const int* __restrict__ esrc,
    const int* __restrict__ perm, const __hip_bfloat16* __restrict__ wswz,
    const float* __restrict__ ball, __hip_bfloat16* __restrict__ msgs, int layer)
{
  __shared__ short8 Wl[8 * 4 * 64];  // 32KB
  const int t = blockIdx.y;
  {
    const float4* wg = (const float4*)(wswz + (size_t)(layer * NT + t) * 16384);
    float4* wl = (float4*)Wl;
    for (int i = threadIdx.x; i < 2048; i += 256) wl[i] = wg[i];
  }
  const int lane = threadIdx.x & 63;
  const int wv   = threadIdx.x >> 6;
  const int hi = lane >> 4, lo = lane & 15;
  float bias_v[8];
#pragma unroll
  for (int nt = 0; nt < 8; ++nt)
    bias_v[nt] = ball[(layer * NT + t) * HH + nt * 16 + lo];
  __syncthreads();

  const int tile_end = min((int)(blockIdx.x + 1) * TPB, NE / 16);
  for (int tile = blockIdx.x * TPB + wv; tile < tile_end; tile += 4) {
    const int e0 = tile * 16;
    const int src = esrc[t * NE + e0 + lo];
    const short* srow = (const short*)(sbf + (size_t)src * HH);
    short8 a[4];
#pragma unroll
    for (int kk = 0; kk < 4; ++kk)
      a[kk] = *(const short8*)(srow + kk * 32 + hi * 8);
    int slot[4];
#pragma unroll
    for (int r = 0; r < 4; ++r) slot[r] = perm[t * NE + e0 + hi * 4 + r];
    f32x4 acc[8];
#pragma unroll
    for (int nt = 0; nt < 8; ++nt) acc[nt] = (f32x4){0.f, 0.f, 0.f, 0.f};
#pragma unroll
    for (int nt = 0; nt < 8; ++nt)
#pragma unroll
      for (int kk = 0; kk < 4; ++kk)
        acc[nt] = __builtin_amdgcn_mfma_f32_16x16x32_bf16(
            a[kk], Wl[(nt * 4 + kk) * 64 + lane], acc[nt], 0, 0, 0);
#pragma unroll
    for (int r = 0; r < 4; ++r) {
      short8 m;
#pragma unroll
      for (int nt = 0; nt < 8; ++nt)
        ((unsigned short*)&m)[nt] = bfbits(acc[nt][r] + bias_v[nt]);
      *(short8*)((short*)msgs + (size_t)slot[r] * HH + lo * 8) = m;
    }
  }
}

// ---------------------------------------------------------------- reduce (CSR gather-sum)
__global__ __launch_bounds__(256) void reduce_kernel(
    const __hip_bfloat16* __restrict__ msgs, const int* __restrict__ row_ptr,
    __hip_bfloat16* __restrict__ agg)
{
  const int lane = threadIdx.x & 63;
  const int n = blockIdx.x * 4 + (threadIdx.x >> 6);
  if (n >= NN) return;
  const int b = row_ptr[n], e = row_ptr[n + 1];
  float a0 = 0.f, a1 = 0.f;
  for (int i = b; i < e; ++i) {
    unsigned int v = *(const unsigned int*)((const short*)msgs + (size_t)i * HH + lane * 2);
    a0 += __uint_as_float(v << 16);
    a1 += __uint_as_float(v & 0xffff0000u);
  }
  unsigned int o = ((unsigned int)bfbits(a1) << 16) | bfbits(a0);
  *(unsigned int*)((short*)agg + (size_t)n * HH + lane * 2) = o;
}

// ---------------------------------------------------------------- GRU (MFMA, XCD-colocated dt-split)
// 1D swizzled grid: wgid = (x%8) + 8*dtg + 32*(x/8) so the 4 dtg-blocks of a
// node-chunk x land on the SAME XCD (round-robin %8) -> A rows L2-shared.
// Bih staged in LDS (24/48 KB); Bhh streamed from L2 (24 KB hot set).
template <int KSL>
__global__ __launch_bounds__(256) void gru_mfma_kernel(
    const __hip_bfloat16* __restrict__ agg,     // sigma order
    const __hip_bfloat16* __restrict__ ibf,     // row-major (layer1)
    const __hip_bfloat16* __restrict__ hbf,     // current state bf16 (read)
    const __hip_bfloat16* __restrict__ Wih_s,
    const __hip_bfloat16* __restrict__ Whh_s,
    const float* __restrict__ bih, const float* __restrict__ bhh,
    __hip_bfloat16* __restrict__ sbf_out)       // next state bf16 (write)
{
  const int wg = blockIdx.x;
  const int xb = (wg >> 5) * 8 + (wg & 7);     // node-chunk
  const int dtg = (wg >> 3) & 3;               // dt-pair group
  if (xb >= XB) return;

  __shared__ short8 BihL[2 * 3 * KSL * 64];    // 24KB (KSL=4) / 48KB (KSL=8)
  {
    const short8* Bih_g = (const short8*)Wih_s;
    for (int i = threadIdx.x; i < 2 * 3 * KSL * 64; i += 256) {
      int lane_i = i & 63, kk = (i >> 6) % KSL, g = ((i >> 6) / KSL) % 3, d2 = (i >> 6) / (KSL * 3);
      BihL[i] = Bih_g[((size_t)(dtg * 2 + d2 + 8 * g) * KSL + kk) * 64 + lane_i];
    }
  }
  const int lane = threadIdx.x & 63;
  const int wv   = threadIdx.x >> 6;
  const int hi = lane >> 4, lo = lane & 15;
  float birv[2], bizv[2], binv[2], bhrv[2], bhzv[2], bhnv[2];
#pragma unroll
  for (int d2 = 0; d2 < 2; ++d2) {
    const int c = (dtg * 2 + d2) * 16 + lo;
    birv[d2] = bih[c]; bizv[d2] = bih[c + 128]; binv[d2] = bih[c + 256];
    bhrv[d2] = bhh[c]; bhzv[d2] = bhh[c + 128]; bhnv[d2] = bhh[c + 256];
  }
  __syncthreads();

  const int pt = xb * 4 + wv;
  if (pt >= NPAIR) return;
  const int t0 = pt * 2;
  const bool two = (t0 + 1 < NTILE);

  short8 ax[2][KSL], ah[2][4];
#pragma unroll
  for (int u = 0; u < 2; ++u) {
    const int nb = ((u && two) ? t0 + 1 : t0) * 16;
    const short* arow = (const short*)(agg + (size_t)(nb + lo) * HH);
    const short* hrow = (const short*)(hbf + (size_t)(nb + lo) * HH);
    if (KSL == 8) {
      const short* irow = (const short*)(ibf + (size_t)(nb + lo) * HH);
#pragma unroll
      for (int kk = 0; kk < 4; ++kk) {
        ax[u][kk]     = *(const short8*)(irow + kk * 32 + hi * 8);
        ax[u][kk + 4] = *(const short8*)(arow + kk * 32 + hi * 8);
      }
    } else {
#pragma unroll
      for (int kk = 0; kk < KSL; ++kk)
        ax[u][kk] = *(const short8*)(arow + kk * 32 + hi * 8);
    }
#pragma unroll
    for (int kk = 0; kk < 4; ++kk)
      ah[u][kk] = *(const short8*)(hrow + kk * 32 + hi * 8);
  }

  const short8* __restrict__ Bhh_g = (const short8*)Whh_s;

  f32x4 aR[2][2], aZ[2][2], aNi[2][2], aNh[2][2];   // [d2][tile]
#pragma unroll
  for (int d2 = 0; d2 < 2; ++d2)
#pragma unroll
    for (int u = 0; u < 2; ++u) {
      aR[d2][u] = (f32x4){0.f, 0.f, 0.f, 0.f};
      aZ[d2][u] = (f32x4){0.f, 0.f, 0.f, 0.f};
      aNi[d2][u] = (f32x4){0.f, 0.f, 0.f, 0.f};
      aNh[d2][u] = (f32x4){0.f, 0.f, 0.f, 0.f};
    }

#pragma unroll
  for (int d2 = 0; d2 < 2; ++d2) {
#pragma unroll
    for (int kk = 0; kk < KSL; ++kk) {
      short8 br = BihL[((d2 * 3 + 0) * KSL + kk) * 64 + lane];
      short8 bz = BihL[((d2 * 3 + 1) * KSL + kk) * 64 + lane];
      short8 bn = BihL[((d2 * 3 + 2) * KSL + kk) * 64 + lane];
#pragma unroll
      for (int u = 0; u < 2; ++u) {
        aR[d2][u]  = __builtin_amdgcn_mfma_f32_16x16x32_bf16(ax[u][kk], br, aR[d2][u], 0, 0, 0);
        aZ[d2][u]  = __builtin_amdgcn_mfma_f32_16x16x32_bf16(ax[u][kk], bz, aZ[d2][u], 0, 0, 0);
        aNi[d2][u] = __builtin_amdgcn_mfma_f32_16x16x32_bf16(ax[u][kk], bn, aNi[d2][u], 0, 0, 0);
      }
    }
#pragma unroll
    for (int kk = 0; kk < 4; ++kk) {
      const int dt = dtg * 2 + d2;
      short8 br = Bhh_g[((size_t)(dt     ) * 4 + kk) * 64 + lane];
      short8 bz = Bhh_g[((size_t)(dt +  8) * 4 + kk) * 64 + lane];
      short8 bn = Bhh_g[((size_t)(dt + 16) * 4 + kk) * 64 + lane];
#pragma unroll
      for (int u = 0; u < 2; ++u) {
        aR[d2][u]  = __builtin_amdgcn_mfma_f32_16x16x32_bf16(ah[u][kk], br, aR[d2][u], 0, 0, 0);
        aZ[d2][u]  = __builtin_amdgcn_mfma_f32_16x16x32_bf16(ah[u][kk], bz, aZ[d2][u], 0, 0, 0);
        aNh[d2][u] = __builtin_amdgcn_mfma_f32_16x16x32_bf16(ah[u][kk], bn, aNh[d2][u], 0, 0, 0);
      }
    }
  }

  const int uend = two ? 2 : 1;
  for (int u = 0; u < uend; ++u) {
    const int nb = (t0 + u) * 16;
#pragma unroll
    for (int d2 = 0; d2 < 2; ++d2) {
      const int c = (dtg * 2 + d2) * 16 + lo;
#pragma unroll
      for (int r = 0; r < 4; ++r) {
        const int node = nb + hi * 4 + r;
        const float rg = sigm(aR[d2][u][r] + birv[d2] + bhrv[d2]);
        const float zg = sigm(aZ[d2][u][r] + bizv[d2] + bhzv[d2]);
        const float ng = tanhf_fast(aNi[d2][u][r] + binv[d2] + rg * (aNh[d2][u][r] + bhnv[d2]));
        const float hc = __bfloat162float(hbf[(size_t)node * HH + c]);
        sbf_out[(size_t)node * HH + c] = __float2bfloat16((1.f - zg) * ng + zg * hc);
      }
    }
  }
}

// ---------------------------------------------------------------- readout (bf16 input)
__global__ __launch_bounds__(256) void readout_kernel(
    const __hip_bfloat16* __restrict__ sbf, const int* __restrict__ ebnd,
    const float* __restrict__ rw, const float* __restrict__ rb,
    float* __restrict__ out, int coff)
{
  __shared__ float sm[4][128];
  const int ex = blockIdx.x / RCH, ch = blockIdx.x % RCH;
  const int s = ebnd[ex], e = ebnd[ex + 1];
  const int lane = threadIdx.x & 63;
  const int wv   = threadIdx.x >> 6;
  const float w0 = rw[2 * lane], w1 = rw[2 * lane + 1], rbv = rb[0];
  float a0 = 0.f, a1 = 0.f;
  for (int n = s + ch * 4 + wv; n < e; n += 4 * RCH) {
    unsigned int v = *(const unsigned int*)((const short*)sbf + (size_t)n * HH + lane * 2);
    const float s0 = __uint_as_float(v << 16);
    const float s1 = __uint_as_float(v & 0xffff0000u);
    float p = s0 * w0 + s1 * w1;
#pragma unroll
    for (int o = 32; o; o >>= 1) p += __shfl_xor(p, o, 64);
    const float g = sigm(p + rbv);
    a0 += g * s0;
    a1 += g * s1;
  }
  sm[wv][2 * lane] = a0;
  sm[wv][2 * lane + 1] = a1;
  __syncthreads();
  if (wv == 0) {
    const int c0 = 2 * lane, c1 = 2 * lane + 1;
    float v0 = sm[0][c0] + sm[1][c0] + sm[2][c0] + sm[3][c0];
    float v1 = sm[0][c1] + sm[1][c1] + sm[2][c1] + sm[3][c1];
    atomicAdd(&out[(size_t)ex * (2 * HH) + coff + c0], v0);
    atomicAdd(&out[(size_t)ex * (2 * HH) + coff + c1], v1);
  }
}

// ---------------------------------------------------------------- launch
extern "C" void kernel_launch(void* const* d_in, const int* in_sizes, int n_in,
                              void* d_out, int out_size, void* d_ws, size_t ws_size,
                              hipStream_t stream)
{
  const int*   cid   = (const int*)d_in[0];
  const int*   tg    = (const int*)d_in[1];
  const int*   esrc  = (const int*)d_in[2];
  const int*   etgt  = (const int*)d_in[3];
  const int*   n2e   = (const int*)d_in[4];
  const float* ctab  = (const float*)d_in[5];
  const float* ttab  = (const float*)d_in[6];
  const float* msgW  = (const float*)d_in[7];
  const float* msgb  = (const float*)d_in[8];
  const float* g0Wih = (const float*)d_in[9];
  const float* g0Whh = (const float*)d_in[10];
  const float* g0bih = (const float*)d_in[11];
  const float* g0bhh = (const float*)d_in[12];
  const float* g1Wih = (const float*)d_in[13];
  const float* g1Whh = (const float*)d_in[14];
  const float* g1bih = (const float*)d_in[15];
  const float* g1bhh = (const float*)d_in[16];
  const float* r1w   = (const float*)d_in[17];
  const float* r1b   = (const float*)d_in[18];
  const float* r2w   = (const float*)d_in[19];
  const float* r2b   = (const float*)d_in[20];

  float* out = (float*)d_out;
  __hip_bfloat16* sb0  = (__hip_bfloat16*)d_ws;
  __hip_bfloat16* sb1  = sb0 + (size_t)NN * HH;
  __hip_bfloat16* ibf  = sb1 + (size_t)NN * HH;
  __hip_bfloat16* agg  = ibf + (size_t)NN * HH;
  __hip_bfloat16* msgs = agg + (size_t)NN * HH;
  __hip_bfloat16* wswz = msgs + (size_t)EDGES * HH;
  __hip_bfloat16* w0ih = wswz + 262144;
  __hip_bfloat16* w0hh = w0ih + 24 * 4 * 512;
  __hip_bfloat16* w1ih = w0hh + 24 * 4 * 512;
  __hip_bfloat16* w1hh = w1ih + 24 * 8 * 512;
  int* row_ptr = (int*)(w1hh + 24 * 4 * 512);
  int* cnt     = row_ptr + NN + 1;
  int* cnt2    = cnt + NN;
  int* perm    = cnt2 + NN;
  int* bsum    = perm + EDGES;
  int* boff    = bsum + SNB;
  int* ebnd    = boff + SNB;

  hipMemsetAsync(d_out, 0, (size_t)NB * 2 * HH * sizeof(float), stream);
  hipMemsetAsync(cnt, 0, (size_t)NN * sizeof(int), stream);
  const int eblocks = (EDGES + 255) / 256;
  hist_kernel<<<eblocks, 256, 0, stream>>>(etgt, cnt);
  scanA_kernel<<<SNB, SBLK, 0, stream>>>(cnt, row_ptr, bsum);
  scanB_kernel<<<1, 128, 0, stream>>>(bsum, boff, row_ptr);
  scanC_kernel<<<SNB, SBLK, 0, stream>>>(row_ptr, cnt2, boff);
  scatter_kernel<<<eblocks, 256, 0, stream>>>(etgt, cnt2, perm);
  exbound_kernel<<<1, 128, 0, stream>>>(n2e, ebnd);

  wswz_all_kernel<<<507904 / 256, 256, 0, stream>>>(msgW, wswz, g0Wih, w0ih, g0Whh, w0hh,
                                                    g1Wih, w1ih, g1Whh, w1hh);
  init_kernel<<<(NN * HH + 255) / 256, 256, 0, stream>>>(cid, tg, ctab, ttab, sb0, ibf);

  dim3 mgrid((NE / 16 + TPB - 1) / TPB, NT);
  const int rblocks = (NN + 3) / 4;
  __hip_bfloat16* cur = sb0;
  __hip_bfloat16* nxt = sb1;
  for (int s = 0; s < 3; ++s) {
    msg_mfma_kernel<<<mgrid, 256, 0, stream>>>(cur, esrc, perm, wswz, msgb, msgs, 0);
    reduce_kernel<<<rblocks, 256, 0, stream>>>(msgs, row_ptr, agg);
    gru_mfma_kernel<4><<<GGRID, 256, 0, stream>>>(agg, ibf, cur, w0ih, w0hh,
                                                  g0bih, g0bhh, nxt);
    __hip_bfloat16* t = cur; cur = nxt; nxt = t;
  }
  readout_kernel<<<NB * RCH, 256, 0, stream>>>(cur, ebnd, r1w, r1b, out, 0);

  for (int s = 0; s < 3; ++s) {
    msg_mfma_kernel<<<mgrid, 256, 0, stream>>>(cur, esrc, perm, wswz, msgb, msgs, 1);
    reduce_kernel<<<rblocks, 256, 0, stream>>>(msgs, row_ptr, agg);
    gru_mfma_kernel<8><<<GGRID, 256, 0, stream>>>(agg, ibf, cur, w1ih, w1hh,
                                                  g1bih, g1bhh, nxt);
    __hip_bfloat16* t = cur; cur = nxt; nxt = t;
  }
  readout_kernel<<<NB * RCH, 256, 0, stream>>>(cur, ebnd, r2w, r2b, out, HH);
}